// Round 1
// baseline (2069.872 us; speedup 1.0000x reference)
//
#include <hip/hip_runtime.h>
#include <hip/hip_bf16.h>
#include <cstdint>

// Problem constants (fixed shapes from the reference harness)
constexpr int T_ = 1024;
constexpr int N_ = 1024;
constexpr int M_ = 1023;
constexpr int B_ = 4;
constexpr int E_ = 1024;
constexpr int H_ = 16;
constexpr int D_ = 64;
constexpr int S_ = N_ + M_;   // 2047

// ---------------------------------------------------------------------------
// dw gate kernel: dw[r*H + h] = sigmoid(node_key_row_r . dw_w[h] + dw_b[h])
// One block per row r (r = m*B + b), 256 threads.
// ---------------------------------------------------------------------------
__global__ void dw_kernel(const float* __restrict__ node_key,
                          const float* __restrict__ dw_w,
                          const float* __restrict__ dw_b,
                          float* __restrict__ dwb)
{
    __shared__ float rowbuf[E_];
    const int r = blockIdx.x;           // 0 .. M*B-1
    const int tid = threadIdx.x;

    for (int idx = tid; idx < E_; idx += 256)
        rowbuf[idx] = node_key[(size_t)r * E_ + idx];
    __syncthreads();

    const int h = tid >> 4;             // 0..15
    const int lane = tid & 15;          // 0..15
    float acc = 0.f;
    const float* wrow = dw_w + (size_t)h * E_;
    for (int k = lane; k < E_; k += 16)
        acc = fmaf(rowbuf[k], wrow[k], acc);
    // reduce across the 16-lane group (consecutive lanes within a wave)
    acc += __shfl_xor(acc, 8);
    acc += __shfl_xor(acc, 4);
    acc += __shfl_xor(acc, 2);
    acc += __shfl_xor(acc, 1);
    if (lane == 0) {
        float x = acc + dw_b[h];
        dwb[(size_t)r * H_ + h] = 1.f / (1.f + __expf(-x));
    }
}

// ---------------------------------------------------------------------------
// Projection GEMM: C[r, c] = sum_k X[r,k] * W[c,k]; then (+bias[c]) * scale,
// optional dw gate multiply, and store either row-major (MODE 0) or
// head-major (B,H,L,D) (MODE 1).  K = N(cols) = E_ = 1024 fixed.
// Block: 256 threads, 64x64 tile, 4x4 per thread, BK=16.
// ---------------------------------------------------------------------------
template<int MODE>
__global__ void proj_gemm(const float* __restrict__ X,
                          const float* __restrict__ W,
                          const float* __restrict__ bias,
                          const float* __restrict__ dwm,
                          float* __restrict__ out,
                          int R, int L, float scale)
{
    __shared__ float Xs[16][65];
    __shared__ float Ws[16][65];

    const int tid = threadIdx.x;
    const int tx = tid & 15;
    const int ty = tid >> 4;
    const int row0 = blockIdx.y * 64;
    const int col0 = blockIdx.x * 64;

    float c[4][4] = {};

    const int rr = tid >> 2;            // 0..63
    const int k4 = (tid & 3) * 4;       // 0,4,8,12

    for (int k0 = 0; k0 < E_; k0 += 16) {
        // X tile 64x16 (transposed into LDS)
        {
            float4 v = make_float4(0.f, 0.f, 0.f, 0.f);
            const int r = row0 + rr;
            if (r < R)
                v = *reinterpret_cast<const float4*>(&X[(size_t)r * E_ + k0 + k4]);
            Xs[k4 + 0][rr] = v.x;
            Xs[k4 + 1][rr] = v.y;
            Xs[k4 + 2][rr] = v.z;
            Xs[k4 + 3][rr] = v.w;
        }
        // W tile 64x16 (rows are output cols)
        {
            const float4 wv = *reinterpret_cast<const float4*>(
                &W[(size_t)(col0 + rr) * E_ + k0 + k4]);
            Ws[k4 + 0][rr] = wv.x;
            Ws[k4 + 1][rr] = wv.y;
            Ws[k4 + 2][rr] = wv.z;
            Ws[k4 + 3][rr] = wv.w;
        }
        __syncthreads();

        #pragma unroll
        for (int kk = 0; kk < 16; ++kk) {
            float a[4], b[4];
            #pragma unroll
            for (int i = 0; i < 4; ++i) a[i] = Xs[kk][ty * 4 + i];
            #pragma unroll
            for (int j = 0; j < 4; ++j) b[j] = Ws[kk][tx * 4 + j];
            #pragma unroll
            for (int i = 0; i < 4; ++i)
                #pragma unroll
                for (int j = 0; j < 4; ++j)
                    c[i][j] = fmaf(a[i], b[j], c[i][j]);
        }
        __syncthreads();
    }

    #pragma unroll
    for (int i = 0; i < 4; ++i) {
        const int r = row0 + ty * 4 + i;
        if (r >= R) continue;
        #pragma unroll
        for (int j = 0; j < 4; ++j) {
            const int cc = col0 + tx * 4 + j;
            float v = (c[i][j] + bias[cc]) * scale;
            if (MODE == 0) {
                out[(size_t)r * E_ + cc] = v;
            } else {
                const int h = cc >> 6;
                const int dd = cc & 63;
                const int l = r >> 2;       // r = l*B + b, B = 4
                const int b = r & 3;
                if (dwm) v *= dwm[(size_t)r * H_ + h];
                out[((size_t)(b * H_ + h) * L + l) * D_ + dd] = v;
            }
        }
    }
}

// ---------------------------------------------------------------------------
// Flash attention over concatenated leaf (N) + node (M) keys/values.
// Grid: (B*H, T/32). Block: 256 threads. 32 q-rows x 32 kv per tile.
// ---------------------------------------------------------------------------
__global__ void attn_kernel(const float* __restrict__ qh,
                            const float* __restrict__ kh,
                            const float* __restrict__ vh,
                            const float* __restrict__ nkh,
                            const float* __restrict__ nvh,
                            const unsigned char* __restrict__ kpm,
                            const unsigned char* __restrict__ npm,
                            float* __restrict__ obuf)
{
    constexpr int PAD = 68;             // float4-aligned row stride (272 B)
    __shared__ float Qs[32][PAD];
    __shared__ float Ks[32][PAD];
    __shared__ float Vs[32][PAD];
    __shared__ float Ps[32][33];
    __shared__ float mrow[32], lrow[32];
    __shared__ int   maskv[32];

    const int bh = blockIdx.x;          // b*H + h
    const int b  = bh >> 4;
    const int h  = bh & 15;
    const int t0 = blockIdx.y * 32;
    const int tid = threadIdx.x;

    // Load Q tile (32 x 64) via float4
    for (int idx = tid; idx < 32 * 16; idx += 256) {
        const int i = idx >> 4, d4 = (idx & 15) * 4;
        const float4 q = *reinterpret_cast<const float4*>(
            &qh[((size_t)bh * T_ + (t0 + i)) * D_ + d4]);
        *reinterpret_cast<float4*>(&Qs[i][d4]) = q;
    }
    if (tid < 32) { mrow[tid] = -3.0e38f; lrow[tid] = 0.f; }
    __syncthreads();

    float acc[8] = {};
    const int rowi = tid >> 3;          // 0..31
    const int sub  = tid & 7;           // 0..7
    const int d0   = sub * 8;

    for (int s0 = 0; s0 < S_; s0 += 32) {
        // --- load K/V tile + mask ---
        for (int idx = tid; idx < 32 * 16; idx += 256) {
            const int j = idx >> 4, d4 = (idx & 15) * 4;
            const int s = s0 + j;
            float4 kv = make_float4(0.f, 0.f, 0.f, 0.f);
            float4 vv = make_float4(0.f, 0.f, 0.f, 0.f);
            if (s < N_) {
                kv = *reinterpret_cast<const float4*>(&kh[((size_t)bh * N_ + s) * D_ + d4]);
                vv = *reinterpret_cast<const float4*>(&vh[((size_t)bh * N_ + s) * D_ + d4]);
            } else if (s < S_) {
                const int sm = s - N_;
                kv = *reinterpret_cast<const float4*>(&nkh[((size_t)bh * M_ + sm) * D_ + d4]);
                vv = *reinterpret_cast<const float4*>(&nvh[((size_t)bh * M_ + sm) * D_ + d4]);
            }
            *reinterpret_cast<float4*>(&Ks[j][d4]) = kv;
            *reinterpret_cast<float4*>(&Vs[j][d4]) = vv;
        }
        if (tid < 32) {
            const int s = s0 + tid;
            int mv;
            if (s < N_)      mv = kpm[(size_t)b * N_ + s] ? 1 : 0;
            else if (s < S_) mv = npm[(size_t)b * M_ + (s - N_)] ? 1 : 0;
            else             mv = 1;
            maskv[tid] = mv;
        }
        __syncthreads();

        // --- scores: thread -> row i, 4 cols ---
        {
            const int i = tid >> 3;
            const int jbase = (tid & 7) * 4;
            float sv[4] = {0.f, 0.f, 0.f, 0.f};
            #pragma unroll 4
            for (int d4 = 0; d4 < 16; ++d4) {
                const float4 q4 = *reinterpret_cast<const float4*>(&Qs[i][d4 * 4]);
                #pragma unroll
                for (int jj = 0; jj < 4; ++jj) {
                    const float4 k4 = *reinterpret_cast<const float4*>(&Ks[jbase + jj][d4 * 4]);
                    sv[jj] = fmaf(q4.x, k4.x, sv[jj]);
                    sv[jj] = fmaf(q4.y, k4.y, sv[jj]);
                    sv[jj] = fmaf(q4.z, k4.z, sv[jj]);
                    sv[jj] = fmaf(q4.w, k4.w, sv[jj]);
                }
            }
            #pragma unroll
            for (int jj = 0; jj < 4; ++jj)
                Ps[i][jbase + jj] = maskv[jbase + jj] ? -3.0e38f : sv[jj];
        }
        __syncthreads();

        // --- online softmax row update (8 threads per row, same wave) ---
        {
            float pv[4];
            float lm = -3.0e38f;
            #pragma unroll
            for (int jj = 0; jj < 4; ++jj) {
                pv[jj] = Ps[rowi][sub + jj * 8];
                lm = fmaxf(lm, pv[jj]);
            }
            lm = fmaxf(lm, __shfl_xor(lm, 1));
            lm = fmaxf(lm, __shfl_xor(lm, 2));
            lm = fmaxf(lm, __shfl_xor(lm, 4));
            const float m_old = mrow[rowi];
            const float m_new = fmaxf(m_old, lm);
            float psum = 0.f;
            #pragma unroll
            for (int jj = 0; jj < 4; ++jj) {
                const float p = __expf(pv[jj] - m_new);
                Ps[rowi][sub + jj * 8] = p;
                psum += p;
            }
            psum += __shfl_xor(psum, 1);
            psum += __shfl_xor(psum, 2);
            psum += __shfl_xor(psum, 4);
            const float f = __expf(m_old - m_new);
            if (sub == 0) {
                mrow[rowi] = m_new;
                lrow[rowi] = lrow[rowi] * f + psum;
            }
            #pragma unroll
            for (int dd = 0; dd < 8; ++dd) acc[dd] *= f;
        }
        __syncthreads();

        // --- acc += P * V ---
        {
            #pragma unroll 4
            for (int j = 0; j < 32; ++j) {
                const float p = Ps[rowi][j];
                const float4 v0 = *reinterpret_cast<const float4*>(&Vs[j][d0]);
                const float4 v1 = *reinterpret_cast<const float4*>(&Vs[j][d0 + 4]);
                acc[0] = fmaf(p, v0.x, acc[0]);
                acc[1] = fmaf(p, v0.y, acc[1]);
                acc[2] = fmaf(p, v0.z, acc[2]);
                acc[3] = fmaf(p, v0.w, acc[3]);
                acc[4] = fmaf(p, v1.x, acc[4]);
                acc[5] = fmaf(p, v1.y, acc[5]);
                acc[6] = fmaf(p, v1.z, acc[6]);
                acc[7] = fmaf(p, v1.w, acc[7]);
            }
        }
        __syncthreads();
    }

    // write o in (T, B, E) layout: e = h*64 + d
    {
        const float linv = 1.f / lrow[rowi];
        const int t = t0 + rowi;
        const size_t base = ((size_t)t * B_ + b) * E_ + h * D_ + d0;
        #pragma unroll
        for (int dd = 0; dd < 8; ++dd)
            obuf[base + dd] = acc[dd] * linv;
    }
}

// ---------------------------------------------------------------------------
extern "C" void kernel_launch(void* const* d_in, const int* in_sizes, int n_in,
                              void* d_out, int out_size, void* d_ws, size_t ws_size,
                              hipStream_t stream) {
    const float* query    = (const float*)d_in[0];
    const float* key      = (const float*)d_in[1];
    const float* node_key = (const float*)d_in[2];
    const float* ipw      = (const float*)d_in[3];
    const float* ipb      = (const float*)d_in[4];
    const float* out_w    = (const float*)d_in[5];
    const float* out_b    = (const float*)d_in[6];
    const float* dw_w     = (const float*)d_in[7];
    const float* dw_b     = (const float*)d_in[8];
    const unsigned char* kpm = (const unsigned char*)d_in[9];
    const unsigned char* npm = (const unsigned char*)d_in[10];
    float* out = (float*)d_out;
    float* ws  = (float*)d_ws;

    // workspace layout (floats)
    float* qh   = ws;                                    // B*H*T*D  = 4194304
    float* kh   = qh  + (size_t)B_ * H_ * T_ * D_;       // B*H*N*D  = 4194304
    float* vh   = kh  + (size_t)B_ * H_ * N_ * D_;       // 4194304
    float* nkh  = vh  + (size_t)B_ * H_ * N_ * D_;       // B*H*M*D  = 4190208
    float* nvh  = nkh + (size_t)B_ * H_ * M_ * D_;       // 4190208
    float* dwb  = nvh + (size_t)B_ * H_ * M_ * D_;       // M*B*H    = 65472
    float* obuf = dwb + (size_t)M_ * B_ * H_;            // T*B*E    = 4194304

    const dim3 blk(256);

    // 1) dw gate (needed by nv projection)
    dw_kernel<<<dim3(M_ * B_), blk, 0, stream>>>(node_key, dw_w, dw_b, dwb);

    // 2) input projections
    const dim3 gq(E_ / 64, (T_ * B_ + 63) / 64);
    const dim3 gk(E_ / 64, (N_ * B_ + 63) / 64);
    const dim3 gn(E_ / 64, (M_ * B_ + 63) / 64);
    proj_gemm<1><<<gq, blk, 0, stream>>>(query,    ipw,              ipb,          nullptr, qh,  T_ * B_, T_, 0.125f);
    proj_gemm<1><<<gk, blk, 0, stream>>>(key,      ipw + E_ * E_,    ipb + E_,     nullptr, kh,  N_ * B_, N_, 1.f);
    proj_gemm<1><<<gk, blk, 0, stream>>>(key,      ipw + 2 * E_ * E_, ipb + 2 * E_, nullptr, vh,  N_ * B_, N_, 1.f);
    proj_gemm<1><<<gn, blk, 0, stream>>>(node_key, ipw + E_ * E_,    ipb + E_,     nullptr, nkh, M_ * B_, M_, 1.f);
    proj_gemm<1><<<gn, blk, 0, stream>>>(node_key, ipw + 2 * E_ * E_, ipb + 2 * E_, dwb,     nvh, M_ * B_, M_, 1.f);

    // 3) attention (flash-style over S = N + M)
    attn_kernel<<<dim3(B_ * H_, T_ / 32), blk, 0, stream>>>(qh, kh, vh, nkh, nvh, kpm, npm, obuf);

    // 4) output projection -> d_out
    proj_gemm<0><<<gq, blk, 0, stream>>>(obuf, out_w, out_b, nullptr, out, T_ * B_, 0, 1.f);
}

// Round 2
// 504.932 us; speedup vs baseline: 4.0993x; 4.0993x over previous
//
#include <hip/hip_runtime.h>
#include <cstdint>
#include <cstddef>

using short8 = __attribute__((ext_vector_type(8))) short;
using f32x4  = __attribute__((ext_vector_type(4))) float;

constexpr int T_ = 1024;
constexpr int N_ = 1024;
constexpr int M_ = 1023;
constexpr int B_ = 4;
constexpr int E_ = 1024;
constexpr int H_ = 16;
constexpr int D_ = 64;

#define MFMA16(a, b, c) __builtin_amdgcn_mfma_f32_16x16x32_bf16((a), (b), (c), 0, 0, 0)

__device__ __forceinline__ unsigned short f2bf(float f) {
    unsigned int u = __float_as_uint(f);
    u += 0x7FFF + ((u >> 16) & 1);          // round-to-nearest-even
    return (unsigned short)(u >> 16);
}
__device__ __forceinline__ float bf2f(unsigned short s) {
    return __uint_as_float(((unsigned int)s) << 16);
}

// ---------------------------------------------------------------------------
// fp32 -> bf16 conversion, with zero-padding from n..npad (npad % 4 == 0)
// ---------------------------------------------------------------------------
__global__ void f2bf_kernel(const float* __restrict__ src,
                            unsigned short* __restrict__ dst, int n, int npad)
{
    int i = (blockIdx.x * 256 + threadIdx.x) * 4;
    if (i >= npad) return;
    if (i + 4 <= n) {
        const float4 v = *reinterpret_cast<const float4*>(src + i);
        ushort4 o;
        o.x = f2bf(v.x); o.y = f2bf(v.y); o.z = f2bf(v.z); o.w = f2bf(v.w);
        *reinterpret_cast<ushort4*>(dst + i) = o;
    } else {
        for (int k = 0; k < 4; ++k)
            dst[i + k] = (i + k < n) ? f2bf(src[i + k]) : (unsigned short)0;
    }
}

// fp32 -> (bf16 hi, bf16 lo) split.  n % 4 == 0
__global__ void f2bf_hilo_kernel(const float* __restrict__ src,
                                 unsigned short* __restrict__ dhi,
                                 unsigned short* __restrict__ dlo, int n)
{
    int i = (blockIdx.x * 256 + threadIdx.x) * 4;
    if (i >= n) return;
    const float4 v = *reinterpret_cast<const float4*>(src + i);
    float a[4] = {v.x, v.y, v.z, v.w};
    ushort4 hi, lo;
    unsigned short h[4], l[4];
    #pragma unroll
    for (int k = 0; k < 4; ++k) {
        h[k] = f2bf(a[k]);
        l[k] = f2bf(a[k] - bf2f(h[k]));
    }
    hi.x = h[0]; hi.y = h[1]; hi.z = h[2]; hi.w = h[3];
    lo.x = l[0]; lo.y = l[1]; lo.z = l[2]; lo.w = l[3];
    *reinterpret_cast<ushort4*>(dhi + i) = hi;
    *reinterpret_cast<ushort4*>(dlo + i) = lo;
}

// ---------------------------------------------------------------------------
// dw gate kernel (fp32, unchanged): dw[r*H+h] = sigmoid(node_key_r . dw_w[h] + dw_b[h])
// ---------------------------------------------------------------------------
__global__ void dw_kernel(const float* __restrict__ node_key,
                          const float* __restrict__ dw_w,
                          const float* __restrict__ dw_b,
                          float* __restrict__ dwb)
{
    __shared__ float rowbuf[E_];
    const int r = blockIdx.x;
    const int tid = threadIdx.x;
    for (int idx = tid; idx < E_; idx += 256)
        rowbuf[idx] = node_key[(size_t)r * E_ + idx];
    __syncthreads();
    const int h = tid >> 4;
    const int lane = tid & 15;
    float acc = 0.f;
    const float* wrow = dw_w + (size_t)h * E_;
    for (int k = lane; k < E_; k += 16)
        acc = fmaf(rowbuf[k], wrow[k], acc);
    acc += __shfl_xor(acc, 8);
    acc += __shfl_xor(acc, 4);
    acc += __shfl_xor(acc, 2);
    acc += __shfl_xor(acc, 1);
    if (lane == 0) {
        float x = acc + dw_b[h];
        dwb[(size_t)r * H_ + h] = 1.f / (1.f + __expf(-x));
    }
}

// ---------------------------------------------------------------------------
// Direct-fragment bf16 MFMA GEMM:  C[r,c] = sum_k A[r,k] * B[c,k]  (K = 1024)
// No LDS; operand fragments read straight from global (L2-resident).
// Block 256 thr = 4 waves; 128x128 tile, 64x64 per wave, 16x16x32 MFMA.
// MFMA layouts (gfx950, measured m89/m91):
//   A-frag: lane holds A[l&15][(l>>4)*8 + i]   i=0..7
//   B-frag: lane holds B[(l>>4)*8 + i][l&15]
//   D     : lane holds D[(l>>4)*4 + j][l&15]   j=0..3
// EPI 0: fp32 row-major out + bias (hi/lo 3-term product, Alo/Blo used)
// EPI 1: bf16 head-major out [b*16+h][t][d], val=(acc+bias)*scale
// EPI 2: bf16 v-panel out [bh][k/32][d][k&31], optional dw gate
// ---------------------------------------------------------------------------
template<int EPI>
__global__ __launch_bounds__(256) void gemm_bf16(
    const unsigned short* __restrict__ A,
    const unsigned short* __restrict__ Alo,
    const unsigned short* __restrict__ Bm,
    const unsigned short* __restrict__ Blo,
    const float* __restrict__ bias,
    const float* __restrict__ dwm,
    void* __restrict__ outp,
    float scale)
{
    const int tid = threadIdx.x;
    const int l = tid & 63, w = tid >> 6;
    const int row0 = blockIdx.y * 128 + (w >> 1) * 64;
    const int col0 = blockIdx.x * 128 + (w & 1) * 64;
    const int rA = row0 + (l & 15);
    const int cB = col0 + (l & 15);
    const int ka = (l >> 4) * 8;

    f32x4 acc[4][4];
    #pragma unroll
    for (int m = 0; m < 4; ++m)
        #pragma unroll
        for (int n = 0; n < 4; ++n)
            acc[m][n] = (f32x4){0.f, 0.f, 0.f, 0.f};

    for (int kt = 0; kt < E_; kt += 32) {
        const int ko = kt + ka;
        short8 av[4], bv[4];
        #pragma unroll
        for (int m = 0; m < 4; ++m)
            av[m] = *reinterpret_cast<const short8*>(&A[(size_t)(rA + m * 16) * E_ + ko]);
        #pragma unroll
        for (int n = 0; n < 4; ++n)
            bv[n] = *reinterpret_cast<const short8*>(&Bm[(size_t)(cB + n * 16) * E_ + ko]);
        #pragma unroll
        for (int m = 0; m < 4; ++m)
            #pragma unroll
            for (int n = 0; n < 4; ++n)
                acc[m][n] = MFMA16(av[m], bv[n], acc[m][n]);
        if (EPI == 0) {
            short8 xv[4];
            #pragma unroll
            for (int m = 0; m < 4; ++m)
                xv[m] = *reinterpret_cast<const short8*>(&Alo[(size_t)(rA + m * 16) * E_ + ko]);
            #pragma unroll
            for (int m = 0; m < 4; ++m)
                #pragma unroll
                for (int n = 0; n < 4; ++n)
                    acc[m][n] = MFMA16(xv[m], bv[n], acc[m][n]);   // Alo * Bhi
            #pragma unroll
            for (int n = 0; n < 4; ++n)
                xv[n] = *reinterpret_cast<const short8*>(&Blo[(size_t)(cB + n * 16) * E_ + ko]);
            #pragma unroll
            for (int m = 0; m < 4; ++m)
                #pragma unroll
                for (int n = 0; n < 4; ++n)
                    acc[m][n] = MFMA16(av[m], xv[n], acc[m][n]);   // Ahi * Blo
        }
    }

    #pragma unroll
    for (int n = 0; n < 4; ++n) {
        const int c = col0 + n * 16 + (l & 15);
        const float bi = bias[c];
        #pragma unroll
        for (int m = 0; m < 4; ++m) {
            #pragma unroll
            for (int j = 0; j < 4; ++j) {
                const int r = row0 + m * 16 + (l >> 4) * 4 + j;
                float v = acc[m][n][j] + bi;
                if (EPI == 0) {
                    ((float*)outp)[(size_t)r * E_ + c] = v;
                } else if (EPI == 1) {
                    v *= scale;
                    const int rn = r >> 2, b = r & 3, hh = c >> 6, dd = c & 63;
                    ((unsigned short*)outp)[((size_t)(b * H_ + hh) * 1024 + rn) * 64 + dd] = f2bf(v);
                } else {
                    const int rn = r >> 2, b = r & 3, hh = c >> 6, dd = c & 63;
                    if (dwm) v *= dwm[(size_t)r * H_ + hh];
                    ((unsigned short*)outp)[(((size_t)(b * H_ + hh) * 32 + (rn >> 5)) * 64 + dd) * 32 + (rn & 31)] = f2bf(v);
                }
            }
        }
    }
}

// ---------------------------------------------------------------------------
// MFMA flash attention over virtual S' = 2048 (1024 leaf + 1023 node + 1 pad).
// Grid (B*H=64, T/64=16), 256 thr = 4 waves; each wave owns 16 q-rows.
// Q frags in registers; K/V frags direct from global (L2); P transposed via
// per-wave XOR-swizzled LDS.  No __syncthreads in the k/v loop.
// ---------------------------------------------------------------------------
__global__ __launch_bounds__(256) void attn_mfma(
    const unsigned short* __restrict__ qbf,
    const unsigned short* __restrict__ kbf,
    const unsigned short* __restrict__ nkbf,
    const unsigned short* __restrict__ vtb,
    const unsigned short* __restrict__ nvtb,
    const unsigned char* __restrict__ kpm,
    const unsigned char* __restrict__ npm,
    unsigned short* __restrict__ ohi,
    unsigned short* __restrict__ olo)
{
    __shared__ float maskS[2048];
    __shared__ unsigned short Pl[4][16 * 64];   // per-wave, XOR-swizzled rows

    const int tid = threadIdx.x;
    const int l = tid & 63, w = tid >> 6;
    const int bh = blockIdx.x, b = bh >> 4, h = bh & 15;
    const int t0 = blockIdx.y * 64;

    for (int s = tid; s < 2048; s += 256) {
        float mv;
        if (s < N_) mv = kpm[(size_t)b * N_ + s] ? -3.0e38f : 0.f;
        else {
            const int m = s - N_;
            mv = (m < M_ && !npm[(size_t)b * M_ + m]) ? 0.f : -3.0e38f;
        }
        maskS[s] = mv;
    }
    __syncthreads();

    const int qrow = t0 + w * 16 + (l & 15);
    const short8 aq0 = *reinterpret_cast<const short8*>(&qbf[((size_t)bh * T_ + qrow) * 64 + (l >> 4) * 8]);
    const short8 aq1 = *reinterpret_cast<const short8*>(&qbf[((size_t)bh * T_ + qrow) * 64 + 32 + (l >> 4) * 8]);

    float mold[4], lr[4];
    #pragma unroll
    for (int j = 0; j < 4; ++j) { mold[j] = -3.0e38f; lr[j] = 0.f; }
    f32x4 acco[4];
    #pragma unroll
    for (int n = 0; n < 4; ++n) acco[n] = (f32x4){0.f, 0.f, 0.f, 0.f};

    unsigned short* const Pw = &Pl[w][0];
    const int prow_r = l & 15;
    const int rofs0 = ((prow_r * 128 + (l >> 4) * 16) ^ ((prow_r & 7) << 4)) >> 1;
    const int rofs1 = ((prow_r * 128 + 64 + (l >> 4) * 16) ^ ((prow_r & 7) << 4)) >> 1;

    for (int s0 = 0; s0 < 2048; s0 += 64) {
        const unsigned short* kb_;
        const unsigned short* vb_;
        int srow;
        if (s0 < N_) { kb_ = kbf;  vb_ = vtb;  srow = s0; }
        else         { kb_ = nkbf; vb_ = nvtb; srow = s0 - N_; }

        // ---- QK^T: S[16 x 64] per wave ----
        f32x4 accs[4];
        #pragma unroll
        for (int n = 0; n < 4; ++n) accs[n] = (f32x4){0.f, 0.f, 0.f, 0.f};
        #pragma unroll
        for (int n = 0; n < 4; ++n) {
            const size_t krow = ((size_t)bh * 1024 + srow + n * 16 + (l & 15)) * 64;
            const short8 k0 = *reinterpret_cast<const short8*>(&kb_[krow + (l >> 4) * 8]);
            const short8 k1 = *reinterpret_cast<const short8*>(&kb_[krow + 32 + (l >> 4) * 8]);
            accs[n] = MFMA16(aq0, k0, accs[n]);
            accs[n] = MFMA16(aq1, k1, accs[n]);
        }

        // ---- mask + online softmax (rows (l>>4)*4+j, cols n*16+(l&15)) ----
        float mz[4];
        #pragma unroll
        for (int n = 0; n < 4; ++n) mz[n] = maskS[s0 + n * 16 + (l & 15)];

        float sv[4][4];
        float mx[4] = {-3.0e38f, -3.0e38f, -3.0e38f, -3.0e38f};
        #pragma unroll
        for (int n = 0; n < 4; ++n)
            #pragma unroll
            for (int j = 0; j < 4; ++j) {
                sv[n][j] = accs[n][j] + mz[n];
                mx[j] = fmaxf(mx[j], sv[n][j]);
            }
        #pragma unroll
        for (int j = 0; j < 4; ++j) {
            mx[j] = fmaxf(mx[j], __shfl_xor(mx[j], 1));
            mx[j] = fmaxf(mx[j], __shfl_xor(mx[j], 2));
            mx[j] = fmaxf(mx[j], __shfl_xor(mx[j], 4));
            mx[j] = fmaxf(mx[j], __shfl_xor(mx[j], 8));
        }
        float f_[4], ps[4];
        #pragma unroll
        for (int j = 0; j < 4; ++j) {
            const float mn = fmaxf(mold[j], mx[j]);
            f_[j] = __expf(mold[j] - mn);
            mold[j] = mn;
            ps[j] = 0.f;
        }
        unsigned short pb[4][4];
        #pragma unroll
        for (int n = 0; n < 4; ++n) {
            const bool msk = (mz[n] != 0.f);
            #pragma unroll
            for (int j = 0; j < 4; ++j) {
                float p = __expf(sv[n][j] - mold[j]);
                p = msk ? 0.f : p;
                pb[n][j] = f2bf(p);
                ps[j] += p;
            }
        }
        #pragma unroll
        for (int j = 0; j < 4; ++j) {
            float p = ps[j];
            p += __shfl_xor(p, 1);
            p += __shfl_xor(p, 2);
            p += __shfl_xor(p, 4);
            p += __shfl_xor(p, 8);
            lr[j] = lr[j] * f_[j] + p;
        }
        #pragma unroll
        for (int n = 0; n < 4; ++n)
            #pragma unroll
            for (int j = 0; j < 4; ++j)
                acco[n][j] *= f_[j];

        // ---- P (D-layout regs) -> LDS (swizzled) -> A-frags ----
        #pragma unroll
        for (int j = 0; j < 4; ++j) {
            const int prow = (l >> 4) * 4 + j;
            const int rb = prow * 128;
            const int sw = (prow & 7) << 4;
            #pragma unroll
            for (int n = 0; n < 4; ++n) {
                const int byte = (rb + (n * 16 + (l & 15)) * 2) ^ sw;
                Pw[byte >> 1] = pb[n][j];
            }
        }
        const short8 ap0 = *reinterpret_cast<const short8*>(Pw + rofs0);
        const short8 ap1 = *reinterpret_cast<const short8*>(Pw + rofs1);

        // ---- PV: O[16 x 64] += P[16 x 64] * V[64 x 64] ----
        const int kp = srow >> 5;
        #pragma unroll
        for (int n = 0; n < 4; ++n) {
            const size_t vr0 = (((size_t)bh * 32 + kp)     * 64 + n * 16 + (l & 15)) * 32;
            const size_t vr1 = (((size_t)bh * 32 + kp + 1) * 64 + n * 16 + (l & 15)) * 32;
            const short8 v0 = *reinterpret_cast<const short8*>(&vb_[vr0 + (l >> 4) * 8]);
            const short8 v1 = *reinterpret_cast<const short8*>(&vb_[vr1 + (l >> 4) * 8]);
            acco[n] = MFMA16(ap0, v0, acco[n]);
            acco[n] = MFMA16(ap1, v1, acco[n]);
        }
    }

    // ---- epilogue: o (t,b,e) as bf16 hi/lo ----
    #pragma unroll
    for (int j = 0; j < 4; ++j) {
        const int t = t0 + w * 16 + (l >> 4) * 4 + j;
        const float linv = 1.f / lr[j];
        #pragma unroll
        for (int n = 0; n < 4; ++n) {
            const float v = acco[n][j] * linv;
            const unsigned short hi = f2bf(v);
            const unsigned short lo = f2bf(v - bf2f(hi));
            const size_t oidx = ((size_t)t * B_ + b) * E_ + h * 64 + n * 16 + (l & 15);
            ohi[oidx] = hi;
            olo[oidx] = lo;
        }
    }
}

// ---------------------------------------------------------------------------
extern "C" void kernel_launch(void* const* d_in, const int* in_sizes, int n_in,
                              void* d_out, int out_size, void* d_ws, size_t ws_size,
                              hipStream_t stream) {
    const float* query    = (const float*)d_in[0];
    const float* key      = (const float*)d_in[1];
    const float* node_key = (const float*)d_in[2];
    const float* ipw      = (const float*)d_in[3];
    const float* ipb      = (const float*)d_in[4];
    const float* out_w    = (const float*)d_in[5];
    const float* out_b    = (const float*)d_in[6];
    const float* dw_w     = (const float*)d_in[7];
    const float* dw_b     = (const float*)d_in[8];
    const unsigned char* kpm = (const unsigned char*)d_in[9];
    const unsigned char* npm = (const unsigned char*)d_in[10];
    float* out = (float*)d_out;

    char* p = (char*)d_ws;
    auto alloc = [&](size_t bytes) {
        char* r = p;
        p += (bytes + 255) & ~(size_t)255;
        return r;
    };
    unsigned short* xq    = (unsigned short*)alloc((size_t)4096 * 1024 * 2);
    unsigned short* xk    = (unsigned short*)alloc((size_t)4096 * 1024 * 2);
    unsigned short* xn    = (unsigned short*)alloc((size_t)4096 * 1024 * 2);  // padded 4092->4096
    unsigned short* wbf   = (unsigned short*)alloc((size_t)3072 * 1024 * 2);
    unsigned short* wohi  = (unsigned short*)alloc((size_t)1024 * 1024 * 2);
    unsigned short* wolo  = (unsigned short*)alloc((size_t)1024 * 1024 * 2);
    unsigned short* qb    = (unsigned short*)alloc((size_t)64 * 1024 * 64 * 2);
    unsigned short* kb_   = (unsigned short*)alloc((size_t)64 * 1024 * 64 * 2);
    unsigned short* nkb   = (unsigned short*)alloc((size_t)64 * 1024 * 64 * 2);
    unsigned short* vtb   = (unsigned short*)alloc((size_t)64 * 1024 * 64 * 2);
    unsigned short* nvtb  = (unsigned short*)alloc((size_t)64 * 1024 * 64 * 2);
    unsigned short* ohi   = (unsigned short*)alloc((size_t)4096 * 1024 * 2);
    unsigned short* olo   = (unsigned short*)alloc((size_t)4096 * 1024 * 2);
    float*          dwb   = (float*)alloc((size_t)4096 * 16 * 4);

    const dim3 blk(256);

    // 1) conversions
    f2bf_kernel<<<dim3(4096), blk, 0, stream>>>(query,    xq, 4194304, 4194304);
    f2bf_kernel<<<dim3(4096), blk, 0, stream>>>(key,      xk, 4194304, 4194304);
    f2bf_kernel<<<dim3(4096), blk, 0, stream>>>(node_key, xn, 4190208, 4194304);
    f2bf_kernel<<<dim3(3072), blk, 0, stream>>>(ipw,      wbf, 3145728, 3145728);
    f2bf_hilo_kernel<<<dim3(1024), blk, 0, stream>>>(out_w, wohi, wolo, 1048576);

    // 2) dw gate
    dw_kernel<<<dim3(M_ * B_), blk, 0, stream>>>(node_key, dw_w, dw_b, dwb);

    // 3) input projections (grid: 8 col-blocks x 32 row-blocks)
    const dim3 gg(8, 32);
    gemm_bf16<1><<<gg, blk, 0, stream>>>(xq, nullptr, wbf,                 nullptr, ipb,        nullptr, qb,   0.125f);
    gemm_bf16<1><<<gg, blk, 0, stream>>>(xk, nullptr, wbf + 1024 * 1024,   nullptr, ipb + 1024, nullptr, kb_,  1.f);
    gemm_bf16<2><<<gg, blk, 0, stream>>>(xk, nullptr, wbf + 2 * 1024 * 1024, nullptr, ipb + 2048, nullptr, vtb,  1.f);
    gemm_bf16<1><<<gg, blk, 0, stream>>>(xn, nullptr, wbf + 1024 * 1024,   nullptr, ipb + 1024, nullptr, nkb,  1.f);
    gemm_bf16<2><<<gg, blk, 0, stream>>>(xn, nullptr, wbf + 2 * 1024 * 1024, nullptr, ipb + 2048, dwb,     nvtb, 1.f);

    // 4) attention
    attn_mfma<<<dim3(64, 16), blk, 0, stream>>>(qb, kb_, nkb, vtb, nvtb, kpm, npm, ohi, olo);

    // 5) output projection (hi/lo 3-term) -> d_out fp32
    gemm_bf16<0><<<gg, blk, 0, stream>>>(ohi, olo, wohi, wolo, out_b, nullptr, out, 1.f);
}

// Round 3
// 358.612 us; speedup vs baseline: 5.7719x; 1.4080x over previous
//
#include <hip/hip_runtime.h>
#include <cstdint>
#include <cstddef>

using short8 = __attribute__((ext_vector_type(8))) short;
using f32x4  = __attribute__((ext_vector_type(4))) float;

constexpr int T_ = 1024;
constexpr int N_ = 1024;
constexpr int M_ = 1023;
constexpr int B_ = 4;
constexpr int E_ = 1024;
constexpr int H_ = 16;
constexpr int D_ = 64;

#define MFMA16(a, b, c) __builtin_amdgcn_mfma_f32_16x16x32_bf16((a), (b), (c), 0, 0, 0)

__device__ __forceinline__ unsigned short f2bf(float f) {
    unsigned int u = __float_as_uint(f);
    u += 0x7FFF + ((u >> 16) & 1);          // round-to-nearest-even
    return (unsigned short)(u >> 16);
}
__device__ __forceinline__ float bf2f(unsigned short s) {
    return __uint_as_float(((unsigned int)s) << 16);
}

// global -> LDS direct copy, 16 B per lane. LDS dest must be wave-uniform;
// HW writes lds_base + lane*16. AS3 numeric value = LDS byte offset (aperture
// is 4GB-aligned, low 32 bits of flat LDS address are the offset — CK idiom).
typedef __attribute__((address_space(1))) const unsigned char gc_byte;
typedef __attribute__((address_space(3))) unsigned char lds_byte;
__device__ __forceinline__ void gload16(const void* g, void* lds) {
    __builtin_amdgcn_global_load_lds((gc_byte*)(uintptr_t)g,
                                     (lds_byte*)(unsigned int)(uintptr_t)lds,
                                     16, 0, 0);
}

// ---------------------------------------------------------------------------
// fp32 -> bf16 conversion, with zero-padding from n..npad (npad % 4 == 0)
// ---------------------------------------------------------------------------
__global__ void f2bf_kernel(const float* __restrict__ src,
                            unsigned short* __restrict__ dst, int n, int npad)
{
    int i = (blockIdx.x * 256 + threadIdx.x) * 4;
    if (i >= npad) return;
    if (i + 4 <= n) {
        const float4 v = *reinterpret_cast<const float4*>(src + i);
        ushort4 o;
        o.x = f2bf(v.x); o.y = f2bf(v.y); o.z = f2bf(v.z); o.w = f2bf(v.w);
        *reinterpret_cast<ushort4*>(dst + i) = o;
    } else {
        for (int k = 0; k < 4; ++k)
            dst[i + k] = (i + k < n) ? f2bf(src[i + k]) : (unsigned short)0;
    }
}

// fp32 -> (bf16 hi, bf16 lo) split.  n % 4 == 0
__global__ void f2bf_hilo_kernel(const float* __restrict__ src,
                                 unsigned short* __restrict__ dhi,
                                 unsigned short* __restrict__ dlo, int n)
{
    int i = (blockIdx.x * 256 + threadIdx.x) * 4;
    if (i >= n) return;
    const float4 v = *reinterpret_cast<const float4*>(src + i);
    float a[4] = {v.x, v.y, v.z, v.w};
    ushort4 hi, lo;
    unsigned short h[4], l[4];
    #pragma unroll
    for (int k = 0; k < 4; ++k) {
        h[k] = f2bf(a[k]);
        l[k] = f2bf(a[k] - bf2f(h[k]));
    }
    hi.x = h[0]; hi.y = h[1]; hi.z = h[2]; hi.w = h[3];
    lo.x = l[0]; lo.y = l[1]; lo.z = l[2]; lo.w = l[3];
    *reinterpret_cast<ushort4*>(dhi + i) = hi;
    *reinterpret_cast<ushort4*>(dlo + i) = lo;
}

// ---------------------------------------------------------------------------
// dw gate kernel (fp32): dw[r*H+h] = sigmoid(node_key_r . dw_w[h] + dw_b[h])
// ---------------------------------------------------------------------------
__global__ void dw_kernel(const float* __restrict__ node_key,
                          const float* __restrict__ dw_w,
                          const float* __restrict__ dw_b,
                          float* __restrict__ dwb)
{
    __shared__ float rowbuf[E_];
    const int r = blockIdx.x;
    const int tid = threadIdx.x;
    for (int idx = tid; idx < E_; idx += 256)
        rowbuf[idx] = node_key[(size_t)r * E_ + idx];
    __syncthreads();
    const int h = tid >> 4;
    const int lane = tid & 15;
    float acc = 0.f;
    const float* wrow = dw_w + (size_t)h * E_;
    for (int k = lane; k < E_; k += 16)
        acc = fmaf(rowbuf[k], wrow[k], acc);
    acc += __shfl_xor(acc, 8);
    acc += __shfl_xor(acc, 4);
    acc += __shfl_xor(acc, 2);
    acc += __shfl_xor(acc, 1);
    if (lane == 0) {
        float x = acc + dw_b[h];
        dwb[(size_t)r * H_ + h] = 1.f / (1.f + __expf(-x));
    }
}

// ---------------------------------------------------------------------------
// Fused input projections: C = A(4096xK=1024) . W^T(1024xK) per blockIdx.z
// segment {Q,K,V,NK,NV}.  m97-style: global_load_lds staging (16B), dbuf
// 2-phase loop, 128x128 tile, BK=32, 4 waves x 64x64, 16 MFMA/K-step.
// Epilogues: 1 = bf16 head-major [bh][t][d] (scale), 2 = bf16 v-panel
// [bh][k/32][d][k&31] (optional dw gate).
// ---------------------------------------------------------------------------
__global__ __launch_bounds__(256) void proj_mfma(
    const unsigned short* __restrict__ xq,
    const unsigned short* __restrict__ xk,
    const unsigned short* __restrict__ xn,
    const unsigned short* __restrict__ wbf,
    const float* __restrict__ ipb,
    const float* __restrict__ dwb,
    unsigned short* __restrict__ qb,
    unsigned short* __restrict__ kb,
    unsigned short* __restrict__ vtb,
    unsigned short* __restrict__ nkb,
    unsigned short* __restrict__ nvtb)
{
    __shared__ unsigned short LDS[2][2][128 * 32];   // [buf][A/W][row*32+col] 32 KB

    const unsigned short* A;
    const unsigned short* W;
    const float* bias;
    const float* dwm = nullptr;
    unsigned short* out;
    int epi;
    float scale = 1.f;
    switch (blockIdx.z) {
      case 0:  A = xq; W = wbf;           bias = ipb;        out = qb;   epi = 1; scale = 0.125f; break;
      case 1:  A = xk; W = wbf + 1048576; bias = ipb + 1024; out = kb;   epi = 1; break;
      case 2:  A = xk; W = wbf + 2097152; bias = ipb + 2048; out = vtb;  epi = 2; break;
      case 3:  A = xn; W = wbf + 1048576; bias = ipb + 1024; out = nkb;  epi = 1; break;
      default: A = xn; W = wbf + 2097152; bias = ipb + 2048; out = nvtb; epi = 2; dwm = dwb; break;
    }

    const int tid = threadIdx.x;
    const int l = tid & 63, w = tid >> 6;
    const int brow = blockIdx.y * 128;
    const int bcol = blockIdx.x * 128;

    // staging: chunk ch covers LDS bytes ch*16 = tile [row=ch>>2][col 8*(ch&3)..]
    const int ch0 = w * 64 + l;            // issue 0: chunks 0..255
    const int ch1 = 256 + w * 64 + l;      // issue 1: chunks 256..511
    const unsigned short* gA0 = A + (size_t)(brow + (ch0 >> 2)) * E_ + (ch0 & 3) * 8;
    const unsigned short* gA1 = A + (size_t)(brow + (ch1 >> 2)) * E_ + (ch1 & 3) * 8;
    const unsigned short* gW0 = W + (size_t)(bcol + (ch0 >> 2)) * E_ + (ch0 & 3) * 8;
    const unsigned short* gW1 = W + (size_t)(bcol + (ch1 >> 2)) * E_ + (ch1 & 3) * 8;

    auto STAGE = [&](int buf, int kt) {
        gload16(gA0 + kt, &LDS[buf][0][(size_t)w * 512]);
        gload16(gA1 + kt, &LDS[buf][0][(size_t)(4 + w) * 512]);
        gload16(gW0 + kt, &LDS[buf][1][(size_t)w * 512]);
        gload16(gW1 + kt, &LDS[buf][1][(size_t)(4 + w) * 512]);
    };

    f32x4 acc[4][4];
    #pragma unroll
    for (int m = 0; m < 4; ++m)
        #pragma unroll
        for (int n = 0; n < 4; ++n)
            acc[m][n] = (f32x4){0.f, 0.f, 0.f, 0.f};

    const int wr = (w >> 1) * 64, wc = (w & 1) * 64;
    const int fr = l & 15, ko = (l >> 4) * 8;

    STAGE(0, 0);
    __syncthreads();
    for (int t = 0; t < 32; ++t) {
        const int cur = t & 1;
        if (t < 31) STAGE(cur ^ 1, (t + 1) * 32);
        short8 av[4], bv[4];
        #pragma unroll
        for (int m = 0; m < 4; ++m)
            av[m] = *reinterpret_cast<const short8*>(&LDS[cur][0][(wr + m * 16 + fr) * 32 + ko]);
        #pragma unroll
        for (int n = 0; n < 4; ++n)
            bv[n] = *reinterpret_cast<const short8*>(&LDS[cur][1][(wc + n * 16 + fr) * 32 + ko]);
        #pragma unroll
        for (int m = 0; m < 4; ++m)
            #pragma unroll
            for (int n = 0; n < 4; ++n)
                acc[m][n] = MFMA16(av[m], bv[n], acc[m][n]);
        if (t < 31) __syncthreads();
    }

    #pragma unroll
    for (int n = 0; n < 4; ++n) {
        const int c = bcol + wc + n * 16 + fr;
        const float bi = bias[c];
        #pragma unroll
        for (int m = 0; m < 4; ++m) {
            #pragma unroll
            for (int j = 0; j < 4; ++j) {
                const int r = brow + wr + m * 16 + (l >> 4) * 4 + j;
                float v = (acc[m][n][j] + bi) * scale;
                const int rn = r >> 2, b = r & 3, hh = c >> 6, dd = c & 63;
                if (epi == 1) {
                    out[((size_t)(b * H_ + hh) * 1024 + rn) * 64 + dd] = f2bf(v);
                } else {
                    if (dwm) v *= dwm[(size_t)r * H_ + hh];
                    out[(((size_t)(b * H_ + hh) * 32 + (rn >> 5)) * 64 + dd) * 32 + (rn & 31)] = f2bf(v);
                }
            }
        }
    }
}

// ---------------------------------------------------------------------------
// Output projection, hi/lo 3-term: C = (Ahi+Alo).(Whi+Wlo)^T dropping lo*lo.
// Same staging structure; 4 staged matrices, 48 MFMA/K-step. fp32 out + bias.
// ---------------------------------------------------------------------------
__global__ __launch_bounds__(256) void outproj_mfma(
    const unsigned short* __restrict__ ahi,
    const unsigned short* __restrict__ alo,
    const unsigned short* __restrict__ whi,
    const unsigned short* __restrict__ wlo,
    const float* __restrict__ out_b,
    float* __restrict__ out)
{
    __shared__ unsigned short LDS[2][4][128 * 32];   // 64 KB

    const int tid = threadIdx.x;
    const int l = tid & 63, w = tid >> 6;
    const int brow = blockIdx.y * 128;
    const int bcol = blockIdx.x * 128;

    const int ch0 = w * 64 + l;
    const int ch1 = 256 + w * 64 + l;
    const size_t ra0 = (size_t)(brow + (ch0 >> 2)) * E_ + (ch0 & 3) * 8;
    const size_t ra1 = (size_t)(brow + (ch1 >> 2)) * E_ + (ch1 & 3) * 8;
    const size_t rb0 = (size_t)(bcol + (ch0 >> 2)) * E_ + (ch0 & 3) * 8;
    const size_t rb1 = (size_t)(bcol + (ch1 >> 2)) * E_ + (ch1 & 3) * 8;

    auto STAGE = [&](int buf, int kt) {
        gload16(ahi + ra0 + kt, &LDS[buf][0][(size_t)w * 512]);
        gload16(ahi + ra1 + kt, &LDS[buf][0][(size_t)(4 + w) * 512]);
        gload16(alo + ra0 + kt, &LDS[buf][1][(size_t)w * 512]);
        gload16(alo + ra1 + kt, &LDS[buf][1][(size_t)(4 + w) * 512]);
        gload16(whi + rb0 + kt, &LDS[buf][2][(size_t)w * 512]);
        gload16(whi + rb1 + kt, &LDS[buf][2][(size_t)(4 + w) * 512]);
        gload16(wlo + rb0 + kt, &LDS[buf][3][(size_t)w * 512]);
        gload16(wlo + rb1 + kt, &LDS[buf][3][(size_t)(4 + w) * 512]);
    };

    f32x4 acc[4][4];
    #pragma unroll
    for (int m = 0; m < 4; ++m)
        #pragma unroll
        for (int n = 0; n < 4; ++n)
            acc[m][n] = (f32x4){0.f, 0.f, 0.f, 0.f};

    const int wr = (w >> 1) * 64, wc = (w & 1) * 64;
    const int fr = l & 15, ko = (l >> 4) * 8;

    STAGE(0, 0);
    __syncthreads();
    for (int t = 0; t < 32; ++t) {
        const int cur = t & 1;
        if (t < 31) STAGE(cur ^ 1, (t + 1) * 32);
        short8 ah[4], al[4], bh[4], bl[4];
        #pragma unroll
        for (int m = 0; m < 4; ++m) {
            ah[m] = *reinterpret_cast<const short8*>(&LDS[cur][0][(wr + m * 16 + fr) * 32 + ko]);
            al[m] = *reinterpret_cast<const short8*>(&LDS[cur][1][(wr + m * 16 + fr) * 32 + ko]);
        }
        #pragma unroll
        for (int n = 0; n < 4; ++n) {
            bh[n] = *reinterpret_cast<const short8*>(&LDS[cur][2][(wc + n * 16 + fr) * 32 + ko]);
            bl[n] = *reinterpret_cast<const short8*>(&LDS[cur][3][(wc + n * 16 + fr) * 32 + ko]);
        }
        #pragma unroll
        for (int m = 0; m < 4; ++m)
            #pragma unroll
            for (int n = 0; n < 4; ++n) {
                acc[m][n] = MFMA16(ah[m], bh[n], acc[m][n]);
                acc[m][n] = MFMA16(al[m], bh[n], acc[m][n]);
                acc[m][n] = MFMA16(ah[m], bl[n], acc[m][n]);
            }
        if (t < 31) __syncthreads();
    }

    #pragma unroll
    for (int n = 0; n < 4; ++n) {
        const int c = bcol + wc + n * 16 + fr;
        const float bi = out_b[c];
        #pragma unroll
        for (int m = 0; m < 4; ++m)
            #pragma unroll
            for (int j = 0; j < 4; ++j) {
                const int r = brow + wr + m * 16 + (l >> 4) * 4 + j;
                out[(size_t)r * E_ + c] = acc[m][n][j] + bi;
            }
    }
}

// ---------------------------------------------------------------------------
// MFMA flash attention over virtual S' = 2048 (1024 leaf + 1023 node + 1 pad).
// Grid (B*H=64, T/64=16), 256 thr = 4 waves; each wave owns 16 q-rows.
// ---------------------------------------------------------------------------
__global__ __launch_bounds__(256) void attn_mfma(
    const unsigned short* __restrict__ qbf,
    const unsigned short* __restrict__ kbf,
    const unsigned short* __restrict__ nkbf,
    const unsigned short* __restrict__ vtb,
    const unsigned short* __restrict__ nvtb,
    const unsigned char* __restrict__ kpm,
    const unsigned char* __restrict__ npm,
    unsigned short* __restrict__ ohi,
    unsigned short* __restrict__ olo)
{
    __shared__ float maskS[2048];
    __shared__ unsigned short Pl[4][16 * 64];   // per-wave, XOR-swizzled rows

    const int tid = threadIdx.x;
    const int l = tid & 63, w = tid >> 6;
    const int bh = blockIdx.x, b = bh >> 4, h = bh & 15;
    const int t0 = blockIdx.y * 64;

    for (int s = tid; s < 2048; s += 256) {
        float mv;
        if (s < N_) mv = kpm[(size_t)b * N_ + s] ? -3.0e38f : 0.f;
        else {
            const int m = s - N_;
            mv = (m < M_ && !npm[(size_t)b * M_ + m]) ? 0.f : -3.0e38f;
        }
        maskS[s] = mv;
    }
    __syncthreads();

    const int qrow = t0 + w * 16 + (l & 15);
    const short8 aq0 = *reinterpret_cast<const short8*>(&qbf[((size_t)bh * T_ + qrow) * 64 + (l >> 4) * 8]);
    const short8 aq1 = *reinterpret_cast<const short8*>(&qbf[((size_t)bh * T_ + qrow) * 64 + 32 + (l >> 4) * 8]);

    float mold[4], lr[4];
    #pragma unroll
    for (int j = 0; j < 4; ++j) { mold[j] = -3.0e38f; lr[j] = 0.f; }
    f32x4 acco[4];
    #pragma unroll
    for (int n = 0; n < 4; ++n) acco[n] = (f32x4){0.f, 0.f, 0.f, 0.f};

    unsigned short* const Pw = &Pl[w][0];
    const int prow_r = l & 15;
    const int rofs0 = ((prow_r * 128 + (l >> 4) * 16) ^ ((prow_r & 7) << 4)) >> 1;
    const int rofs1 = ((prow_r * 128 + 64 + (l >> 4) * 16) ^ ((prow_r & 7) << 4)) >> 1;

    for (int s0 = 0; s0 < 2048; s0 += 64) {
        const unsigned short* kb_;
        const unsigned short* vb_;
        int srow;
        if (s0 < N_) { kb_ = kbf;  vb_ = vtb;  srow = s0; }
        else         { kb_ = nkbf; vb_ = nvtb; srow = s0 - N_; }

        // ---- QK^T ----
        f32x4 accs[4];
        #pragma unroll
        for (int n = 0; n < 4; ++n) accs[n] = (f32x4){0.f, 0.f, 0.f, 0.f};
        #pragma unroll
        for (int n = 0; n < 4; ++n) {
            const size_t krow = ((size_t)bh * 1024 + srow + n * 16 + (l & 15)) * 64;
            const short8 k0 = *reinterpret_cast<const short8*>(&kb_[krow + (l >> 4) * 8]);
            const short8 k1 = *reinterpret_cast<const short8*>(&kb_[krow + 32 + (l >> 4) * 8]);
            accs[n] = MFMA16(aq0, k0, accs[n]);
            accs[n] = MFMA16(aq1, k1, accs[n]);
        }

        // ---- mask + online softmax ----
        float mz[4];
        #pragma unroll
        for (int n = 0; n < 4; ++n) mz[n] = maskS[s0 + n * 16 + (l & 15)];

        float sv[4][4];
        float mx[4] = {-3.0e38f, -3.0e38f, -3.0e38f, -3.0e38f};
        #pragma unroll
        for (int n = 0; n < 4; ++n)
            #pragma unroll
            for (int j = 0; j < 4; ++j) {
                sv[n][j] = accs[n][j] + mz[n];
                mx[j] = fmaxf(mx[j], sv[n][j]);
            }
        #pragma unroll
        for (int j = 0; j < 4; ++j) {
            mx[j] = fmaxf(mx[j], __shfl_xor(mx[j], 1));
            mx[j] = fmaxf(mx[j], __shfl_xor(mx[j], 2));
            mx[j] = fmaxf(mx[j], __shfl_xor(mx[j], 4));
            mx[j] = fmaxf(mx[j], __shfl_xor(mx[j], 8));
        }
        float f_[4], ps[4];
        #pragma unroll
        for (int j = 0; j < 4; ++j) {
            const float mn = fmaxf(mold[j], mx[j]);
            f_[j] = __expf(mold[j] - mn);
            mold[j] = mn;
            ps[j] = 0.f;
        }
        unsigned short pb[4][4];
        #pragma unroll
        for (int n = 0; n < 4; ++n) {
            const bool msk = (mz[n] != 0.f);
            #pragma unroll
            for (int j = 0; j < 4; ++j) {
                float p = __expf(sv[n][j] - mold[j]);
                p = msk ? 0.f : p;
                pb[n][j] = f2bf(p);
                ps[j] += p;
            }
        }
        #pragma unroll
        for (int j = 0; j < 4; ++j) {
            float p = ps[j];
            p += __shfl_xor(p, 1);
            p += __shfl_xor(p, 2);
            p += __shfl_xor(p, 4);
            p += __shfl_xor(p, 8);
            lr[j] = lr[j] * f_[j] + p;
        }
        #pragma unroll
        for (int n = 0; n < 4; ++n)
            #pragma unroll
            for (int j = 0; j < 4; ++j)
                acco[n][j] *= f_[j];

        // ---- P -> LDS (swizzled) -> A-frags ----
        #pragma unroll
        for (int j = 0; j < 4; ++j) {
            const int prow = (l >> 4) * 4 + j;
            const int rb = prow * 128;
            const int sw = (prow & 7) << 4;
            #pragma unroll
            for (int n = 0; n < 4; ++n) {
                const int byte = (rb + (n * 16 + (l & 15)) * 2) ^ sw;
                Pw[byte >> 1] = pb[n][j];
            }
        }
        const short8 ap0 = *reinterpret_cast<const short8*>(Pw + rofs0);
        const short8 ap1 = *reinterpret_cast<const short8*>(Pw + rofs1);

        // ---- PV ----
        const int kp = srow >> 5;
        #pragma unroll
        for (int n = 0; n < 4; ++n) {
            const size_t vr0 = (((size_t)bh * 32 + kp)     * 64 + n * 16 + (l & 15)) * 32;
            const size_t vr1 = (((size_t)bh * 32 + kp + 1) * 64 + n * 16 + (l & 15)) * 32;
            const short8 v0 = *reinterpret_cast<const short8*>(&vb_[vr0 + (l >> 4) * 8]);
            const short8 v1 = *reinterpret_cast<const short8*>(&vb_[vr1 + (l >> 4) * 8]);
            acco[n] = MFMA16(ap0, v0, acco[n]);
            acco[n] = MFMA16(ap1, v1, acco[n]);
        }
    }

    // ---- epilogue: o (t,b,e) as bf16 hi/lo ----
    #pragma unroll
    for (int j = 0; j < 4; ++j) {
        const int t = t0 + w * 16 + (l >> 4) * 4 + j;
        const float linv = 1.f / lr[j];
        #pragma unroll
        for (int n = 0; n < 4; ++n) {
            const float v = acco[n][j] * linv;
            const unsigned short hi = f2bf(v);
            const unsigned short lo = f2bf(v - bf2f(hi));
            const size_t oidx = ((size_t)t * B_ + b) * E_ + h * 64 + n * 16 + (l & 15);
            ohi[oidx] = hi;
            olo[oidx] = lo;
        }
    }
}

// ---------------------------------------------------------------------------
extern "C" void kernel_launch(void* const* d_in, const int* in_sizes, int n_in,
                              void* d_out, int out_size, void* d_ws, size_t ws_size,
                              hipStream_t stream) {
    const float* query    = (const float*)d_in[0];
    const float* key      = (const float*)d_in[1];
    const float* node_key = (const float*)d_in[2];
    const float* ipw      = (const float*)d_in[3];
    const float* ipb      = (const float*)d_in[4];
    const float* out_w    = (const float*)d_in[5];
    const float* out_b    = (const float*)d_in[6];
    const float* dw_w     = (const float*)d_in[7];
    const float* dw_b     = (const float*)d_in[8];
    const unsigned char* kpm = (const unsigned char*)d_in[9];
    const unsigned char* npm = (const unsigned char*)d_in[10];
    float* out = (float*)d_out;

    char* p = (char*)d_ws;
    auto alloc = [&](size_t bytes) {
        char* r = p;
        p += (bytes + 255) & ~(size_t)255;
        return r;
    };
    unsigned short* xq    = (unsigned short*)alloc((size_t)4096 * 1024 * 2);
    unsigned short* xk    = (unsigned short*)alloc((size_t)4096 * 1024 * 2);
    unsigned short* xn    = (unsigned short*)alloc((size_t)4096 * 1024 * 2);  // padded 4092->4096
    unsigned short* wbf   = (unsigned short*)alloc((size_t)3072 * 1024 * 2);
    unsigned short* wohi  = (unsigned short*)alloc((size_t)1024 * 1024 * 2);
    unsigned short* wolo  = (unsigned short*)alloc((size_t)1024 * 1024 * 2);
    unsigned short* qb    = (unsigned short*)alloc((size_t)64 * 1024 * 64 * 2);
    unsigned short* kb_   = (unsigned short*)alloc((size_t)64 * 1024 * 64 * 2);
    unsigned short* nkb   = (unsigned short*)alloc((size_t)64 * 1024 * 64 * 2);
    unsigned short* vtb   = (unsigned short*)alloc((size_t)64 * 1024 * 64 * 2);
    unsigned short* nvtb  = (unsigned short*)alloc((size_t)64 * 1024 * 64 * 2);
    unsigned short* ohi   = (unsigned short*)alloc((size_t)4096 * 1024 * 2);
    unsigned short* olo   = (unsigned short*)alloc((size_t)4096 * 1024 * 2);
    float*          dwb   = (float*)alloc((size_t)4096 * 16 * 4);

    const dim3 blk(256);

    // 1) conversions
    f2bf_kernel<<<dim3(4096), blk, 0, stream>>>(query,    xq, 4194304, 4194304);
    f2bf_kernel<<<dim3(4096), blk, 0, stream>>>(key,      xk, 4194304, 4194304);
    f2bf_kernel<<<dim3(4096), blk, 0, stream>>>(node_key, xn, 4190208, 4194304);
    f2bf_kernel<<<dim3(3072), blk, 0, stream>>>(ipw,      wbf, 3145728, 3145728);
    f2bf_hilo_kernel<<<dim3(1024), blk, 0, stream>>>(out_w, wohi, wolo, 1048576);

    // 2) dw gate
    dw_kernel<<<dim3(M_ * B_), blk, 0, stream>>>(node_key, dw_w, dw_b, dwb);

    // 3) fused input projections: grid (8 col, 32 row, 5 segments)
    proj_mfma<<<dim3(8, 32, 5), blk, 0, stream>>>(xq, xk, xn, wbf, ipb, dwb,
                                                  qb, kb_, vtb, nkb, nvtb);

    // 4) attention
    attn_mfma<<<dim3(64, 16), blk, 0, stream>>>(qb, kb_, nkb, vtb, nvtb, kpm, npm, ohi, olo);

    // 5) output projection (hi/lo 3-term) -> d_out fp32
    outproj_mfma<<<dim3(8, 32), blk, 0, stream>>>(ohi, olo, wohi, wolo, out_b, out);
}